// Round 3
// baseline (423.920 us; speedup 1.0000x reference)
//
#include <hip/hip_runtime.h>
#include <hip/hip_bf16.h>
#include <stdint.h>

typedef __attribute__((ext_vector_type(8))) short short8;
typedef __attribute__((ext_vector_type(4))) float f32x4;

#define N_NODES 16384
#define D_IN    512
#define D_HID   256
#define D_OUT   64
#define S_SAMP  4096

__device__ __forceinline__ unsigned short f2bf(float f) {
  __hip_bfloat16 h = __float2bfloat16(f);
  union { __hip_bfloat16 h; unsigned short u; } cv; cv.h = h; return cv.u;
}

// C += scale * bf16(optional-relu(A_f32[gathered rows])) @ Bt^T
// A: [M][lda] f32 (row gather via arow). Bt: [BN][K] bf16 row-major (N==BN).
// C: [M][ldc] f32, pre-zeroed, atomic accumulate. Grid = (M/BM) * kChunks.
// 2-phase pipeline: double-buffered As/Bs, stage(t+1) issued before compute(t),
// ONE barrier per K-step.
template<int BM, int BN, int BK, bool RELU_A>
__global__ __launch_bounds__(256)
void gemm_tn(const float* __restrict__ A, int lda,
             const int* __restrict__ arow,
             const unsigned short* __restrict__ Bt, int ldb,
             float* __restrict__ C, int ldc,
             int K, int kChunks, float scale)
{
  static_assert(BM == 64 && (BK == 32 || BK == 64) && (BN == 64 || BN == 256), "tile");
  constexpr int CH    = BK / 8;      // 16B chunks per LDS row
  constexpr int RPS   = 512 / BK;    // rows per 1KB slab (64 lanes x 16B)
  constexpr int SLABS = BN / RPS;
  constexpr int SLABW = SLABS / 4;   // slabs per wave
  constexpr int AV    = BK / 16;     // f32x4 loads per thread (A tile)
  constexpr int AC    = BK / 32;     // short8 chunks per thread (A tile)

  const int mt  = blockIdx.x / kChunks;
  const int kc  = blockIdx.x % kChunks;
  const int kLen = K / kChunks;
  const int k0   = kc * kLen;
  const int nt   = kLen / BK;
  const int tid  = threadIdx.x;
  const int lane = tid & 63;
  const int wid  = tid >> 6;
  const int l16  = lane & 15;
  const int lg   = lane >> 4;

  __shared__ unsigned short As[2][BM * BK];
  __shared__ unsigned short Bs[2][BN * BK];

  constexpr int WN  = (BN == 256) ? 4 : 2;
  constexpr int WM  = 4 / WN;
  constexpr int WTM = BM / WM;
  constexpr int WTN = BN / WN;
  constexpr int MF  = WTM / 16;
  constexpr int NF  = WTN / 16;
  const int wrow = wid / WN;
  const int wcol = wid % WN;

  f32x4 acc[MF][NF] = {};

  // ---- A staging mapping: 256 threads, 4 per row, BK/4 f32 each ----
  const int am   = tid >> 2;
  const int aseg = tid & 3;
  const int arowIdx = mt * BM + am;
  const size_t rowg = arow ? (size_t)arow[arowIdx] : (size_t)arowIdx;
  const float* aBase = A + rowg * (size_t)lda + k0 + aseg * (BK / 4);

  // ---- B staging: global_load_lds, linear LDS dest + pre-swizzled source ----
  const int brow = lane / CH;                          // row within slab
  const int bcol = 8 * ((lane % CH) ^ (brow & (CH - 1)));
  const unsigned short* bSrc = Bt + (size_t)brow * ldb + k0 + bcol;

  f32x4 av[AV];

  auto loadA = [&](int ks) {
    #pragma unroll
    for (int i = 0; i < AV; ++i) av[i] = *(const f32x4*)(aBase + ks + 4 * i);
  };
  auto writeA = [&](int buf) {
    if (RELU_A) {
      #pragma unroll
      for (int i = 0; i < AV; ++i)
        #pragma unroll
        for (int j = 0; j < 4; ++j) av[i][j] = fmaxf(av[i][j], 0.f);
    }
    #pragma unroll
    for (int c = 0; c < AC; ++c) {
      short8 s;
      s[0]=f2bf(av[2*c][0]);   s[1]=f2bf(av[2*c][1]);
      s[2]=f2bf(av[2*c][2]);   s[3]=f2bf(av[2*c][3]);
      s[4]=f2bf(av[2*c+1][0]); s[5]=f2bf(av[2*c+1][1]);
      s[6]=f2bf(av[2*c+1][2]); s[7]=f2bf(av[2*c+1][3]);
      const int g = (aseg * AC + c) ^ (am & (CH - 1));
      *(short8*)&As[buf][am * BK + g * 8] = s;
    }
  };
  auto issueB = [&](int buf, int ks) {
    #pragma unroll
    for (int i = 0; i < SLABW; ++i) {
      const int s = wid * SLABW + i;
      __builtin_amdgcn_global_load_lds(
          (const __attribute__((address_space(1))) uint32_t*)(bSrc + (size_t)s * RPS * ldb + ks),
          (__attribute__((address_space(3))) uint32_t*)(&Bs[buf][s * 512]),
          16, 0, 0);
    }
  };
  auto compute = [&](int buf) {
    #pragma unroll
    for (int kk = 0; kk < BK / 32; ++kk) {
      const int gk = kk * 4 + lg;
      short8 af[MF], bfr[NF];
      #pragma unroll
      for (int fm = 0; fm < MF; ++fm) {
        const int m = wrow * WTM + fm * 16 + l16;
        af[fm] = *(const short8*)&As[buf][m * BK + ((gk ^ (m & (CH - 1))) * 8)];
      }
      #pragma unroll
      for (int fn = 0; fn < NF; ++fn) {
        const int n = wcol * WTN + fn * 16 + l16;
        bfr[fn] = *(const short8*)&Bs[buf][n * BK + ((gk ^ (n & (CH - 1))) * 8)];
      }
      #pragma unroll
      for (int fm = 0; fm < MF; ++fm)
        #pragma unroll
        for (int fn = 0; fn < NF; ++fn)
          acc[fm][fn] = __builtin_amdgcn_mfma_f32_16x16x32_bf16(
              af[fm], bfr[fn], acc[fm][fn], 0, 0, 0);
    }
  };

  // ---- prologue: stage tile 0 ----
  loadA(0);
  issueB(0, 0);
  writeA(0);
  __syncthreads();      // drains vmcnt (B-lds) + lgkm (A ds_write)

  int cur = 0;
  for (int t = 0; t < nt; ++t) {
    const bool more = (t + 1 < nt);
    if (more) {
      loadA((t + 1) * BK);          // issue A reg-loads early (T14 split)
      issueB(cur ^ 1, (t + 1) * BK);
    }
    compute(cur);
    if (more) writeA(cur ^ 1);      // cvt + ds_write after compute
    __syncthreads();
    cur ^= 1;
  }

  // ---- epilogue: scaled f32 atomic add ----
  #pragma unroll
  for (int fm = 0; fm < MF; ++fm)
    #pragma unroll
    for (int fn = 0; fn < NF; ++fn)
      #pragma unroll
      for (int j = 0; j < 4; ++j) {
        const int r = mt * BM + wrow * WTM + fm * 16 + lg * 4 + j;
        const int c = wcol * WTN + fn * 16 + l16;
        atomicAdd(&C[(size_t)r * ldc + c], scale * acc[fm][fn][j]);
      }
}

// transpose-convert weights: W1t[j][i] = bf16(W1[i][j]), W2t likewise
__global__ void conv_w_t(const float* __restrict__ W1, const float* __restrict__ W2,
                         unsigned short* __restrict__ W1t, unsigned short* __restrict__ W2t) {
  const int idx = blockIdx.x * 256 + threadIdx.x;
  if (idx < D_IN * D_HID) {
    const int j = idx / D_IN, i = idx % D_IN;
    W1t[idx] = f2bf(W1[(size_t)i * D_HID + j]);
  }
  if (idx < D_HID * D_OUT) {
    const int j = idx / D_HID, i = idx % D_HID;
    W2t[idx] = f2bf(W2[(size_t)i * D_OUT + j]);
  }
}

// BextT[c][rows[r]] = bf16(relu(G[r][c] + bias[c]))   (BextT pre-zeroed, [ncol][N_NODES])
__global__ void ep_scatter_t(const float* __restrict__ G, const float* __restrict__ bias,
                             const int* __restrict__ rows, unsigned short* __restrict__ BextT,
                             int ncol, int total) {
  const int idx = blockIdx.x * 256 + threadIdx.x;
  if (idx >= total) return;
  const int c = idx / S_SAMP;
  const int r = idx & (S_SAMP - 1);
  float v = G[(size_t)r * ncol + c] + bias[c];
  v = v > 0.f ? v : 0.f;
  BextT[(size_t)c * N_NODES + rows[r]] = f2bf(v);
}

extern "C" void kernel_launch(void* const* d_in, const int* in_sizes, int n_in,
                              void* d_out, int out_size, void* d_ws, size_t ws_size,
                              hipStream_t stream) {
  const float* X     = (const float*)d_in[0];
  const float* A_hat = (const float*)d_in[1];
  const float* W1    = (const float*)d_in[2];
  const float* b1    = (const float*)d_in[3];
  const float* W2    = (const float*)d_in[4];
  const float* b2    = (const float*)d_in[5];
  const int*   l0    = (const int*)d_in[6];
  const int*   l1    = (const int*)d_in[7];
  float* out = (float*)d_out;

  if (ws_size < (size_t)(20u << 20)) return;
  char* ws = (char*)d_ws;
  // zeroed region: [HextT 8M][PextT 2M][G1 4M][G2 4M][G3 1M] = 19 MB contiguous
  unsigned short* HextT = (unsigned short*)(ws);                      // [256][16384]
  unsigned short* PextT = (unsigned short*)(ws + (8  << 20));         // [64][16384]
  float* G1 = (float*)(ws + (10 << 20));                              // [S][256]
  float* G2 = (float*)(ws + (14 << 20));                              // [S][256]
  float* G3 = (float*)(ws + (18 << 20));                              // [S][64]
  unsigned short* W1t = (unsigned short*)(ws + (19 << 20));           // [256][512]
  unsigned short* W2t = (unsigned short*)(ws + (19 << 20) + (256 << 10)); // [64][256]

  hipMemsetAsync(ws,  0, (size_t)(19u << 20), stream);
  hipMemsetAsync(out, 0, (size_t)N_NODES * D_OUT * 4, stream);

  conv_w_t<<<512, 256, 0, stream>>>(W1, W2, W1t, W2t);

  // L0 feature: G1 = X[l0] @ W1          M=4096 K=512 N=256
  gemm_tn<64, 256, 32, false><<<(S_SAMP / 64) * 4, 256, 0, stream>>>(
      X, D_IN, l0, W1t, D_IN, G1, D_HID, D_IN, 4, 1.0f);
  // HextT[:, l0[j]] = bf16(relu(G1[j] + b1))
  ep_scatter_t<<<(S_SAMP * D_HID + 255) / 256, 256, 0, stream>>>(
      G1, b1, l0, HextT, D_HID, S_SAMP * D_HID);

  // L0 agg: G2 = 4 * A_hat[l1, :] @ Hext  M=4096 K=16384 N=256
  gemm_tn<64, 256, 32, false><<<(S_SAMP / 64) * 16, 256, 0, stream>>>(
      A_hat, N_NODES, l1, HextT, N_NODES, G2, D_HID, N_NODES, 16, 4.0f);

  // L1 feature: G3 = relu(G2) @ W2        M=4096 K=256 N=64  (relu fused into A-path)
  gemm_tn<64, 64, 64, true><<<(S_SAMP / 64) * 4, 256, 0, stream>>>(
      G2, D_HID, nullptr, W2t, D_HID, G3, D_OUT, D_HID, 4, 1.0f);
  // PextT[:, l1[j]] = bf16(relu(G3[j] + b2))
  ep_scatter_t<<<(S_SAMP * D_OUT + 255) / 256, 256, 0, stream>>>(
      G3, b2, l1, PextT, D_OUT, S_SAMP * D_OUT);

  // L1 agg: out = 4 * A_hat @ Pext        M=16384 K=16384 N=64
  gemm_tn<64, 64, 64, false><<<(N_NODES / 64) * 4, 256, 0, stream>>>(
      A_hat, N_NODES, nullptr, PextT, N_NODES, out, D_OUT, N_NODES, 4, 4.0f);
}